// Round 1
// baseline (447.679 us; speedup 1.0000x reference)
//
#include <hip/hip_runtime.h>
#include <hip/hip_bf16.h>

typedef __attribute__((ext_vector_type(4))) float f32x4;
typedef __attribute__((ext_vector_type(8))) short s16x8;
typedef __attribute__((ext_vector_type(4))) short s16x4;
typedef unsigned short u16;

// ---- helpers -------------------------------------------------------------

__device__ __forceinline__ f32x4 mfma16(s16x8 a, s16x8 b, f32x4 c) {
    return __builtin_amdgcn_mfma_f32_16x16x32_bf16(a, b, c, 0, 0, 0);
}

// RNE fp32 -> bf16 (bit trick)
__device__ __forceinline__ u16 bf(float f) {
    union { float f; unsigned u; } x; x.f = f;
    return (u16)((x.u + 0x7fffu + ((x.u >> 16) & 1u)) >> 16);
}
__device__ __forceinline__ unsigned pkbf(float a, float b) {
    union { float f; unsigned u; } x, y; x.f = a; y.f = b;
    unsigned ra = x.u + 0x7fffu + ((x.u >> 16) & 1u);
    unsigned rb = y.u + 0x7fffu + ((y.u >> 16) & 1u);
    return (ra >> 16) | (rb & 0xffff0000u);
}
__device__ __forceinline__ s16x8 cvt8(f32x4 lo, f32x4 hi) {
    union { s16x8 v; unsigned u[4]; } r;
    r.u[0] = pkbf(lo.x, lo.y);
    r.u[1] = pkbf(lo.z, lo.w);
    r.u[2] = pkbf(hi.x, hi.y);
    r.u[3] = pkbf(hi.z, hi.w);
    return r.v;
}

// ---- K0: fp32 -> bf16 convert -------------------------------------------

__global__ __launch_bounds__(256) void cvt_kernel(const float* __restrict__ src,
                                                  u16* __restrict__ dst, int n4) {
    int i = blockIdx.x * 256 + threadIdx.x;
    if (i < n4) {
        f32x4 v = ((const f32x4*)src)[i];
        union { s16x4 v; unsigned u[2]; } r;
        r.u[0] = pkbf(v.x, v.y);
        r.u[1] = pkbf(v.z, v.w);
        ((s16x4*)dst)[i] = r.v;
    }
}

// ---- K1: QKV projections -------------------------------------------------
// q[h][n][e] = sum_d x[n][d]*Wq[h][e][d] + bq[h][e]   (stored bf16, (H,N,E))
// k,v same but stored transposed (H,E,N) for the downstream B-operand.
// grid: blockIdx.x = bn*16 + bm,  bn = mat*16+h (48), bm = m-tile of 256 rows.

__global__ __launch_bounds__(256) void qkv_kernel(
        const u16* __restrict__ xb, const u16* __restrict__ wb,
        const float* __restrict__ bq, const float* __restrict__ bk,
        const float* __restrict__ bv,
        u16* __restrict__ qo, u16* __restrict__ kTo, u16* __restrict__ vTo) {
    int bm   = blockIdx.x & 15;
    int bn   = blockIdx.x >> 4;           // mat*16 + h
    int mat  = bn >> 4, h = bn & 15;
    int lane = threadIdx.x & 63, w = threadIdx.x >> 6;
    int l15  = lane & 15, quad = lane >> 4;
    int row0 = bm * 256 + w * 64;

    const u16* A = xb + (size_t)(row0 + l15) * 1024 + quad * 8;
    const u16* B = wb + (size_t)bn * 65536 + (size_t)l15 * 1024 + quad * 8;

    f32x4 acc[4][4] = {};
    for (int k = 0; k < 1024; k += 32) {
        s16x8 a[4], b[4];
#pragma unroll
        for (int i = 0; i < 4; i++) a[i] = *(const s16x8*)(A + i * 16 * 1024 + k);
#pragma unroll
        for (int j = 0; j < 4; j++) b[j] = *(const s16x8*)(B + j * 16 * 1024 + k);
#pragma unroll
        for (int i = 0; i < 4; i++)
#pragma unroll
            for (int j = 0; j < 4; j++) acc[i][j] = mfma16(a[i], b[j], acc[i][j]);
    }

    const float* bias = (mat == 0) ? bq : (mat == 1 ? bk : bv);
#pragma unroll
    for (int j = 0; j < 4; j++) {
        int e = j * 16 + l15;
        float bb = bias[h * 64 + e];
#pragma unroll
        for (int i = 0; i < 4; i++) {
            int n0 = row0 + i * 16 + quad * 4;
            f32x4 c = acc[i][j];
            if (mat == 0) {
                u16* p = qo + ((size_t)h * 4096 + n0) * 64 + e;
#pragma unroll
                for (int r = 0; r < 4; r++) p[(size_t)r * 64] = bf(c[r] + bb);
            } else {
                u16* p = (mat == 1 ? kTo : vTo) + ((size_t)h * 64 + e) * 4096 + n0;
                union { s16x4 v; u16 s[4]; } pk;
#pragma unroll
                for (int r = 0; r < 4; r++) pk.s[r] = bf(c[r] + bb);
                *(s16x4*)p = pk.v;
            }
        }
    }
}

// ---- K2: kp/vp = Ew @ k, Fw @ v (split-K=4, fp32 atomics) ---------------
// acc[p][h][j][e] += sum_{n in chunk} Ew[h][j][n] * kT[h][e][n]
// grid: b = p*256 + h*16 + jt*4 + ks   (512 blocks)

__global__ __launch_bounds__(256) void kpvp_kernel(
        const float* __restrict__ Ew, const float* __restrict__ Fw,
        const u16* __restrict__ kT, const u16* __restrict__ vT,
        float* __restrict__ accb) {
    int b    = blockIdx.x;
    int ks   = b & 3, jt = (b >> 2) & 3, h = (b >> 4) & 15, p = b >> 8;
    int lane = threadIdx.x & 63, w = threadIdx.x >> 6;
    int l15  = lane & 15, quad = lane >> 4;

    const float* A = (p ? Fw : Ew) +
        ((size_t)h * 256 + jt * 64 + w * 16 + l15) * 4096 + ks * 1024 + quad * 8;
    const u16* B = (p ? vT : kT) +
        (size_t)h * 64 * 4096 + (size_t)l15 * 4096 + ks * 1024 + quad * 8;

    f32x4 acc[4] = {};
    for (int k = 0; k < 1024; k += 32) {
        f32x4 a0 = *(const f32x4*)(A + k);
        f32x4 a1 = *(const f32x4*)(A + k + 4);
        s16x8 av = cvt8(a0, a1);
#pragma unroll
        for (int j = 0; j < 4; j++) {
            s16x8 bv = *(const s16x8*)(B + (size_t)j * 16 * 4096 + k);
            acc[j] = mfma16(av, bv, acc[j]);
        }
    }
    float* out = accb + ((size_t)(p * 16 + h) * 256 + jt * 64 + w * 16 + quad * 4) * 64;
#pragma unroll
    for (int j = 0; j < 4; j++) {
        int e = j * 16 + l15;
#pragma unroll
        for (int r = 0; r < 4; r++) atomicAdd(out + (size_t)r * 64 + e, acc[j][r]);
    }
}

// ---- K3: bias + pack: kp bf16 (pre-scaled by 1/8), vp transposed bf16 ----

__global__ __launch_bounds__(256) void packkv_kernel(
        const float* __restrict__ accb, const float* __restrict__ Eb,
        const float* __restrict__ Fb, u16* __restrict__ kp, u16* __restrict__ vpT) {
    int idx = blockIdx.x * 256 + threadIdx.x;
    int p = idx >> 18, h = (idx >> 14) & 15, j = (idx >> 6) & 255, e = idx & 63;
    float v = accb[idx];
    if (p == 0) {
        v += Eb[h * 256 + j];
        kp[((size_t)(h * 256 + j)) * 64 + e] = bf(v * 0.125f);   // fold 1/sqrt(64)
    } else {
        v += Fb[h * 256 + j];
        vpT[((size_t)(h * 64 + e)) * 256 + j] = bf(v);
    }
}

// ---- K4: attention: score -> softmax -> PV ------------------------------
// grid: blockIdx.x = h*64 + bm  (64-row q tiles); 4 waves x 16 rows each.

__global__ __launch_bounds__(256) void attn_kernel(
        const u16* __restrict__ q, const u16* __restrict__ kp,
        const u16* __restrict__ vpT, u16* __restrict__ zs) {
    __shared__ u16 ps[4][16][256];
    int bm   = blockIdx.x & 63, h = blockIdx.x >> 6;
    int lane = threadIdx.x & 63, w = threadIdx.x >> 6;
    int l15  = lane & 15, quad = lane >> 4;
    int nbase = bm * 64 + w * 16;

    // scores: s[jt] covers cols jt*16..+15, rows quad*4+r (n = nbase + that)
    f32x4 s[16] = {};
    const u16* qp  = q  + ((size_t)h * 4096 + nbase + l15) * 64 + quad * 8;
    const u16* kpp = kp + ((size_t)h * 256 + l15) * 64 + quad * 8;
#pragma unroll
    for (int e0 = 0; e0 < 64; e0 += 32) {
        s16x8 a = *(const s16x8*)(qp + e0);
#pragma unroll
        for (int jt = 0; jt < 16; jt++) {
            s16x8 b = *(const s16x8*)(kpp + jt * 16 * 64 + e0);
            s[jt] = mfma16(a, b, s[jt]);
        }
    }

    // softmax over 256 cols per row (scale already folded into kp)
    float lsum[4];
#pragma unroll
    for (int r = 0; r < 4; r++) {
        float m = s[0][r];
#pragma unroll
        for (int jt = 1; jt < 16; jt++) m = fmaxf(m, s[jt][r]);
        m = fmaxf(m, __shfl_xor(m, 1));
        m = fmaxf(m, __shfl_xor(m, 2));
        m = fmaxf(m, __shfl_xor(m, 4));
        m = fmaxf(m, __shfl_xor(m, 8));
        float l = 0.f;
#pragma unroll
        for (int jt = 0; jt < 16; jt++) {
            float pv = __expf(s[jt][r] - m);
            s[jt][r] = pv;
            l += pv;
        }
        l += __shfl_xor(l, 1);
        l += __shfl_xor(l, 2);
        l += __shfl_xor(l, 4);
        l += __shfl_xor(l, 8);
        lsum[r] = l;
    }

    // P -> LDS (bf16), per-wave region
#pragma unroll
    for (int jt = 0; jt < 16; jt++)
#pragma unroll
        for (int r = 0; r < 4; r++)
            ps[w][quad * 4 + r][jt * 16 + l15] = bf(s[jt][r]);
    __syncthreads();

    // PV: z[n][e] = sum_j P[n][j] * vp[j][e]
    f32x4 z[4] = {};
    const u16* vp = vpT + ((size_t)h * 64 + l15) * 256 + quad * 8;
#pragma unroll
    for (int kj = 0; kj < 8; kj++) {
        s16x8 a = *(const s16x8*)&ps[w][l15][kj * 32 + quad * 8];
#pragma unroll
        for (int et = 0; et < 4; et++) {
            s16x8 b = *(const s16x8*)(vp + et * 16 * 256 + kj * 32);
            z[et] = mfma16(a, b, z[et]);
        }
    }
#pragma unroll
    for (int et = 0; et < 4; et++) {
        int e = et * 16 + l15;
        u16* o = zs + ((size_t)(nbase + quad * 4)) * 1024 + h * 64 + e;
#pragma unroll
        for (int r = 0; r < 4; r++) o[(size_t)r * 1024] = bf(z[et][r] / lsum[r]);
    }
}

// ---- K5: out = zs @ Wo^T  (fp32 out) ------------------------------------

__global__ __launch_bounds__(256) void out_kernel(
        const u16* __restrict__ zs, const float* __restrict__ Wo,
        float* __restrict__ out) {
    int lane = threadIdx.x & 63, w = threadIdx.x >> 6;
    int l15  = lane & 15, quad = lane >> 4;
    int row0 = blockIdx.x * 128 + w * 32;

    const u16* A  = zs + (size_t)(row0 + l15) * 1024 + quad * 8;
    const float* B = Wo + (size_t)l15 * 1024 + quad * 8;

    f32x4 acc[2][4] = {};
    for (int k = 0; k < 1024; k += 32) {
        s16x8 a0 = *(const s16x8*)(A + k);
        s16x8 a1 = *(const s16x8*)(A + 16 * 1024 + k);
#pragma unroll
        for (int nt = 0; nt < 4; nt++) {
            f32x4 b0 = *(const f32x4*)(B + nt * 16 * 1024 + k);
            f32x4 b1 = *(const f32x4*)(B + nt * 16 * 1024 + k + 4);
            s16x8 bv = cvt8(b0, b1);
            acc[0][nt] = mfma16(a0, bv, acc[0][nt]);
            acc[1][nt] = mfma16(a1, bv, acc[1][nt]);
        }
    }
#pragma unroll
    for (int mt = 0; mt < 2; mt++)
#pragma unroll
        for (int nt = 0; nt < 4; nt++) {
            int e = nt * 16 + l15;
            int n0 = row0 + mt * 16 + quad * 4;
            float* o = out + (size_t)n0 * 64 + e;
#pragma unroll
            for (int r = 0; r < 4; r++) o[(size_t)r * 64] = acc[mt][nt][r];
        }
}

// ---- launch --------------------------------------------------------------

extern "C" void kernel_launch(void* const* d_in, const int* in_sizes, int n_in,
                              void* d_out, int out_size, void* d_ws, size_t ws_size,
                              hipStream_t stream) {
    const float* x  = (const float*)d_in[0];
    const float* Wq = (const float*)d_in[1];
    const float* bq = (const float*)d_in[2];
    const float* Wk = (const float*)d_in[3];
    const float* bk = (const float*)d_in[4];
    const float* Wv = (const float*)d_in[5];
    const float* bv = (const float*)d_in[6];
    const float* Ew = (const float*)d_in[7];
    const float* Eb = (const float*)d_in[8];
    const float* Fw = (const float*)d_in[9];
    const float* Fb = (const float*)d_in[10];
    const float* Wo = (const float*)d_in[11];

    char* ws = (char*)d_ws;
    u16*   qb   = (u16*)(ws + 0);          // H*N*E bf16            8 MB
    u16*   kT   = (u16*)(ws + 8388608);    // H*E*N bf16            8 MB
    u16*   vT   = (u16*)(ws + 16777216);   // H*E*N bf16            8 MB
    u16*   zsb  = (u16*)(ws + 25165824);   // N*(H*E) bf16          8 MB
    float* accb = (float*)(ws + 33554432); // 2*H*256*64 fp32       2 MB
    u16*   kp   = (u16*)(ws + 35651584);   // H*256*64 bf16       0.5 MB
    u16*   vpT  = (u16*)(ws + 36175872);   // H*64*256 bf16       0.5 MB
    u16*   xb   = (u16*)(ws + 36700160);   // N*D bf16              8 MB
    u16*   wb   = (u16*)(ws + 45088768);   // 3*H*E*D bf16          6 MB

    hipMemsetAsync(accb, 0, (size_t)2 * 16 * 256 * 64 * sizeof(float), stream);

    cvt_kernel<<<4096, 256, 0, stream>>>(x,  xb, 1048576);
    cvt_kernel<<<1024, 256, 0, stream>>>(Wq, wb,           262144);
    cvt_kernel<<<1024, 256, 0, stream>>>(Wk, wb + 1048576, 262144);
    cvt_kernel<<<1024, 256, 0, stream>>>(Wv, wb + 2097152, 262144);

    qkv_kernel<<<768, 256, 0, stream>>>(xb, wb, bq, bk, bv, qb, kT, vT);
    kpvp_kernel<<<512, 256, 0, stream>>>(Ew, Fw, kT, vT, accb);
    packkv_kernel<<<2048, 256, 0, stream>>>(accb, Eb, Fb, kp, vpT);
    attn_kernel<<<1024, 256, 0, stream>>>(qb, kp, vpT, zsb);
    out_kernel<<<32, 256, 0, stream>>>(zsb, Wo, (float*)d_out);
}

// Round 2
// 301.280 us; speedup vs baseline: 1.4859x; 1.4859x over previous
//
#include <hip/hip_runtime.h>
#include <hip/hip_bf16.h>

typedef __attribute__((ext_vector_type(4))) float f32x4;
typedef __attribute__((ext_vector_type(8))) short s16x8;
typedef __attribute__((ext_vector_type(4))) short s16x4;
typedef unsigned short u16;

// ---- helpers -------------------------------------------------------------

__device__ __forceinline__ f32x4 mfma16(s16x8 a, s16x8 b, f32x4 c) {
    return __builtin_amdgcn_mfma_f32_16x16x32_bf16(a, b, c, 0, 0, 0);
}

// RNE fp32 -> bf16 (bit trick)
__device__ __forceinline__ u16 bf(float f) {
    union { float f; unsigned u; } x; x.f = f;
    return (u16)((x.u + 0x7fffu + ((x.u >> 16) & 1u)) >> 16);
}
__device__ __forceinline__ unsigned pkbf(float a, float b) {
    union { float f; unsigned u; } x, y; x.f = a; y.f = b;
    unsigned ra = x.u + 0x7fffu + ((x.u >> 16) & 1u);
    unsigned rb = y.u + 0x7fffu + ((y.u >> 16) & 1u);
    return (ra >> 16) | (rb & 0xffff0000u);
}
__device__ __forceinline__ s16x8 cvt8(f32x4 lo, f32x4 hi) {
    union { s16x8 v; unsigned u[4]; } r;
    r.u[0] = pkbf(lo.x, lo.y);
    r.u[1] = pkbf(lo.z, lo.w);
    r.u[2] = pkbf(hi.x, hi.y);
    r.u[3] = pkbf(hi.z, hi.w);
    return r.v;
}

// async global->LDS, 16B per lane (wave-uniform LDS base + lane*16)
__device__ __forceinline__ void gl_lds16(const u16* g, u16* l) {
    __builtin_amdgcn_global_load_lds(
        (const __attribute__((address_space(1))) unsigned*)g,
        (__attribute__((address_space(3))) unsigned*)l, 16, 0, 0);
}

// ---- K0: fp32 -> bf16 convert -------------------------------------------

__global__ __launch_bounds__(256) void cvt_kernel(const float* __restrict__ src,
                                                  u16* __restrict__ dst, int n4) {
    int i = blockIdx.x * 256 + threadIdx.x;
    if (i < n4) {
        f32x4 v = ((const f32x4*)src)[i];
        union { s16x4 v; unsigned u[2]; } r;
        r.u[0] = pkbf(v.x, v.y);
        r.u[1] = pkbf(v.z, v.w);
        ((s16x4*)dst)[i] = r.v;
    }
}

// ---- K1: QKV projections, m97-style LDS-staged 128x128 GEMM -------------
// C[4096 x 3072] = xb[4096 x 1024] * wb^T[3072 x 1024], both K-contiguous.
// grid: blockIdx.x = by*24 + bx; by = m-tile (32), bx = n-tile (24).
// q written (H,N,E); k,v written transposed (H,E,N).

__global__ __launch_bounds__(256, 2) void qkv_kernel(
        const u16* __restrict__ xb, const u16* __restrict__ wb,
        const float* __restrict__ bq, const float* __restrict__ bk,
        const float* __restrict__ bv,
        u16* __restrict__ qo, u16* __restrict__ kTo, u16* __restrict__ vTo) {
    __shared__ u16 As[128 * 32];
    __shared__ u16 Bs[128 * 32];
    int bx   = blockIdx.x % 24;
    int by   = blockIdx.x / 24;
    int tid  = threadIdx.x;
    int lane = tid & 63, w = tid >> 6;
    int l15  = lane & 15, quad = lane >> 4;
    int wr   = w >> 1, wc = w & 1;

    // staging addresses: thread t loads 16B chunk (t&3) of row (t>>2)
    const u16* Ag = xb + (size_t)(by * 128 + (tid >> 2)) * 1024 + (tid & 3) * 8;
    const u16* Bg = wb + (size_t)(bx * 128 + (tid >> 2)) * 1024 + (tid & 3) * 8;
    u16* Al = As + tid * 8;   // byte offset tid*16 (contiguous per wave)
    u16* Bl = Bs + tid * 8;

    const u16* abase = As + (wr * 64 + l15) * 32 + quad * 8;
    const u16* bbase = Bs + (wc * 64 + l15) * 32 + quad * 8;

    f32x4 acc[4][4] = {};
    for (int k0 = 0; k0 < 1024; k0 += 32) {
        gl_lds16(Ag + k0, Al);
        gl_lds16(Ag + 64 * 1024 + k0, Al + 64 * 32);
        gl_lds16(Bg + k0, Bl);
        gl_lds16(Bg + 64 * 1024 + k0, Bl + 64 * 32);
        __syncthreads();           // drains vmcnt -> LDS tiles valid
        s16x8 a[4], b[4];
#pragma unroll
        for (int mi = 0; mi < 4; mi++) a[mi] = *(const s16x8*)(abase + mi * 16 * 32);
#pragma unroll
        for (int nj = 0; nj < 4; nj++) b[nj] = *(const s16x8*)(bbase + nj * 16 * 32);
#pragma unroll
        for (int mi = 0; mi < 4; mi++)
#pragma unroll
            for (int nj = 0; nj < 4; nj++) acc[mi][nj] = mfma16(a[mi], b[nj], acc[mi][nj]);
        __syncthreads();           // protect LDS before next stage
    }

    int fblk = (bx * 128 + wc * 64) >> 6;     // 0..47 feature block
    int mat  = fblk >> 4, h = fblk & 15;
    const float* bias = (mat == 0) ? bq : (mat == 1 ? bk : bv);
#pragma unroll
    for (int nj = 0; nj < 4; nj++) {
        int e = nj * 16 + l15;
        float bb = bias[h * 64 + e];
#pragma unroll
        for (int mi = 0; mi < 4; mi++) {
            int n0 = by * 128 + wr * 64 + mi * 16 + quad * 4;
            f32x4 c = acc[mi][nj];
            if (mat == 0) {
                u16* p = qo + ((size_t)h * 4096 + n0) * 64 + e;
#pragma unroll
                for (int r = 0; r < 4; r++) p[(size_t)r * 64] = bf(c[r] + bb);
            } else {
                u16* p = (mat == 1 ? kTo : vTo) + ((size_t)h * 64 + e) * 4096 + n0;
                union { s16x4 v; u16 s[4]; } pk;
#pragma unroll
                for (int r = 0; r < 4; r++) pk.s[r] = bf(c[r] + bb);
                *(s16x4*)p = pk.v;
            }
        }
    }
}

// ---- K2: kp/vp = Ew @ k, Fw @ v (split-K=8, fp32 atomics) ---------------
// grid: b = p*512 + h*32 + jt*8 + ks   (1024 blocks)

__global__ __launch_bounds__(256) void kpvp_kernel(
        const float* __restrict__ Ew, const float* __restrict__ Fw,
        const u16* __restrict__ kT, const u16* __restrict__ vT,
        float* __restrict__ accb) {
    int b    = blockIdx.x;
    int ks   = b & 7, jt = (b >> 3) & 3, h = (b >> 5) & 15, p = b >> 9;
    int lane = threadIdx.x & 63, w = threadIdx.x >> 6;
    int l15  = lane & 15, quad = lane >> 4;

    const float* A = (p ? Fw : Ew) +
        ((size_t)h * 256 + jt * 64 + w * 16 + l15) * 4096 + ks * 512 + quad * 8;
    const u16* B = (p ? vT : kT) +
        (size_t)h * 64 * 4096 + (size_t)l15 * 4096 + ks * 512 + quad * 8;

    f32x4 acc[4] = {};
    for (int k = 0; k < 512; k += 32) {
        f32x4 a0 = *(const f32x4*)(A + k);
        f32x4 a1 = *(const f32x4*)(A + k + 4);
        s16x8 av = cvt8(a0, a1);
#pragma unroll
        for (int j = 0; j < 4; j++) {
            s16x8 bv = *(const s16x8*)(B + (size_t)j * 16 * 4096 + k);
            acc[j] = mfma16(av, bv, acc[j]);
        }
    }
    float* out = accb + ((size_t)(p * 16 + h) * 256 + jt * 64 + w * 16 + quad * 4) * 64;
#pragma unroll
    for (int j = 0; j < 4; j++) {
        int e = j * 16 + l15;
#pragma unroll
        for (int r = 0; r < 4; r++) atomicAdd(out + (size_t)r * 64 + e, acc[j][r]);
    }
}

// ---- K3: bias + pack: kp bf16 (pre-scaled by 1/8), vp transposed bf16 ----

__global__ __launch_bounds__(256) void packkv_kernel(
        const float* __restrict__ accb, const float* __restrict__ Eb,
        const float* __restrict__ Fb, u16* __restrict__ kp, u16* __restrict__ vpT) {
    int idx = blockIdx.x * 256 + threadIdx.x;
    int p = idx >> 18, h = (idx >> 14) & 15, j = (idx >> 6) & 255, e = idx & 63;
    float v = accb[idx];
    if (p == 0) {
        v += Eb[h * 256 + j];
        kp[((size_t)(h * 256 + j)) * 64 + e] = bf(v * 0.125f);   // fold 1/sqrt(64)
    } else {
        v += Fb[h * 256 + j];
        vpT[((size_t)(h * 64 + e)) * 256 + j] = bf(v);
    }
}

// ---- K4: attention: score -> softmax -> PV ------------------------------
// grid: blockIdx.x = h*64 + bm  (64-row q tiles); 4 waves x 16 rows each.

__global__ __launch_bounds__(256) void attn_kernel(
        const u16* __restrict__ q, const u16* __restrict__ kp,
        const u16* __restrict__ vpT, u16* __restrict__ zs) {
    __shared__ u16 ps[4][16][256];
    int bm   = blockIdx.x & 63, h = blockIdx.x >> 6;
    int lane = threadIdx.x & 63, w = threadIdx.x >> 6;
    int l15  = lane & 15, quad = lane >> 4;
    int nbase = bm * 64 + w * 16;

    f32x4 s[16] = {};
    const u16* qp  = q  + ((size_t)h * 4096 + nbase + l15) * 64 + quad * 8;
    const u16* kpp = kp + ((size_t)h * 256 + l15) * 64 + quad * 8;
#pragma unroll
    for (int e0 = 0; e0 < 64; e0 += 32) {
        s16x8 a = *(const s16x8*)(qp + e0);
#pragma unroll
        for (int jt = 0; jt < 16; jt++) {
            s16x8 b = *(const s16x8*)(kpp + jt * 16 * 64 + e0);
            s[jt] = mfma16(a, b, s[jt]);
        }
    }

    float lsum[4];
#pragma unroll
    for (int r = 0; r < 4; r++) {
        float m = s[0][r];
#pragma unroll
        for (int jt = 1; jt < 16; jt++) m = fmaxf(m, s[jt][r]);
        m = fmaxf(m, __shfl_xor(m, 1));
        m = fmaxf(m, __shfl_xor(m, 2));
        m = fmaxf(m, __shfl_xor(m, 4));
        m = fmaxf(m, __shfl_xor(m, 8));
        float l = 0.f;
#pragma unroll
        for (int jt = 0; jt < 16; jt++) {
            float pv = __expf(s[jt][r] - m);
            s[jt][r] = pv;
            l += pv;
        }
        l += __shfl_xor(l, 1);
        l += __shfl_xor(l, 2);
        l += __shfl_xor(l, 4);
        l += __shfl_xor(l, 8);
        lsum[r] = l;
    }

#pragma unroll
    for (int jt = 0; jt < 16; jt++)
#pragma unroll
        for (int r = 0; r < 4; r++)
            ps[w][quad * 4 + r][jt * 16 + l15] = bf(s[jt][r]);
    __syncthreads();

    f32x4 z[4] = {};
    const u16* vp = vpT + ((size_t)h * 64 + l15) * 256 + quad * 8;
#pragma unroll
    for (int kj = 0; kj < 8; kj++) {
        s16x8 a = *(const s16x8*)&ps[w][l15][kj * 32 + quad * 8];
#pragma unroll
        for (int et = 0; et < 4; et++) {
            s16x8 b = *(const s16x8*)(vp + et * 16 * 256 + kj * 32);
            z[et] = mfma16(a, b, z[et]);
        }
    }
#pragma unroll
    for (int et = 0; et < 4; et++) {
        int e = et * 16 + l15;
        u16* o = zs + ((size_t)(nbase + quad * 4)) * 1024 + h * 64 + e;
#pragma unroll
        for (int r = 0; r < 4; r++) o[(size_t)r * 1024] = bf(z[et][r] / lsum[r]);
    }
}

// ---- K5: out = zs @ Wo^T, split-K=4 with fp32 atomics -------------------
// grid: blockIdx.x = bm*4 + ks  (128 blocks); Wo pre-converted to bf16.

__global__ __launch_bounds__(256) void out_kernel(
        const u16* __restrict__ zs, const u16* __restrict__ wob,
        float* __restrict__ out) {
    int ks   = blockIdx.x & 3;
    int bm   = blockIdx.x >> 2;
    int lane = threadIdx.x & 63, w = threadIdx.x >> 6;
    int l15  = lane & 15, quad = lane >> 4;
    int row0 = bm * 128 + w * 32;

    const u16* A = zs  + (size_t)(row0 + l15) * 1024 + ks * 256 + quad * 8;
    const u16* B = wob + (size_t)l15 * 1024 + ks * 256 + quad * 8;

    f32x4 acc[2][4] = {};
    for (int k = 0; k < 256; k += 32) {
        s16x8 a0 = *(const s16x8*)(A + k);
        s16x8 a1 = *(const s16x8*)(A + 16 * 1024 + k);
#pragma unroll
        for (int nt = 0; nt < 4; nt++) {
            s16x8 bv = *(const s16x8*)(B + (size_t)nt * 16 * 1024 + k);
            acc[0][nt] = mfma16(a0, bv, acc[0][nt]);
            acc[1][nt] = mfma16(a1, bv, acc[1][nt]);
        }
    }
#pragma unroll
    for (int mt = 0; mt < 2; mt++)
#pragma unroll
        for (int nt = 0; nt < 4; nt++) {
            int e = nt * 16 + l15;
            int n0 = row0 + mt * 16 + quad * 4;
            float* o = out + (size_t)n0 * 64 + e;
#pragma unroll
            for (int r = 0; r < 4; r++) atomicAdd(o + (size_t)r * 64, acc[mt][nt][r]);
        }
}

// ---- launch --------------------------------------------------------------

extern "C" void kernel_launch(void* const* d_in, const int* in_sizes, int n_in,
                              void* d_out, int out_size, void* d_ws, size_t ws_size,
                              hipStream_t stream) {
    const float* x  = (const float*)d_in[0];
    const float* Wq = (const float*)d_in[1];
    const float* bq = (const float*)d_in[2];
    const float* Wk = (const float*)d_in[3];
    const float* bk = (const float*)d_in[4];
    const float* Wv = (const float*)d_in[5];
    const float* bv = (const float*)d_in[6];
    const float* Ew = (const float*)d_in[7];
    const float* Eb = (const float*)d_in[8];
    const float* Fw = (const float*)d_in[9];
    const float* Fb = (const float*)d_in[10];
    const float* Wo = (const float*)d_in[11];

    char* ws = (char*)d_ws;
    u16*   qb   = (u16*)(ws + 0);          // H*N*E bf16            8 MB
    u16*   kT   = (u16*)(ws + 8388608);    // H*E*N bf16            8 MB
    u16*   vT   = (u16*)(ws + 16777216);   // H*E*N bf16            8 MB
    u16*   zsb  = (u16*)(ws + 25165824);   // N*(H*E) bf16          8 MB
    float* accb = (float*)(ws + 33554432); // 2*H*256*64 fp32       2 MB
    u16*   kp   = (u16*)(ws + 35651584);   // H*256*64 bf16       0.5 MB
    u16*   vpT  = (u16*)(ws + 36175872);   // H*64*256 bf16       0.5 MB
    u16*   xb   = (u16*)(ws + 36700160);   // N*D bf16              8 MB
    u16*   wb   = (u16*)(ws + 45088768);   // 3*H*E*D bf16          6 MB
    u16*   wob  = (u16*)(ws + 51380224);   // E*(H*E) bf16       128 KB

    hipMemsetAsync(accb, 0, (size_t)2 * 16 * 256 * 64 * sizeof(float), stream);
    hipMemsetAsync(d_out, 0, (size_t)4096 * 64 * sizeof(float), stream);

    cvt_kernel<<<4096, 256, 0, stream>>>(x,  xb, 1048576);
    cvt_kernel<<<1024, 256, 0, stream>>>(Wq, wb,           262144);
    cvt_kernel<<<1024, 256, 0, stream>>>(Wk, wb + 1048576, 262144);
    cvt_kernel<<<1024, 256, 0, stream>>>(Wv, wb + 2097152, 262144);
    cvt_kernel<<<64,   256, 0, stream>>>(Wo, wob, 16384);

    qkv_kernel<<<768, 256, 0, stream>>>(xb, wb, bq, bk, bv, qb, kT, vT);
    kpvp_kernel<<<1024, 256, 0, stream>>>(Ew, Fw, kT, vT, accb);
    packkv_kernel<<<2048, 256, 0, stream>>>(accb, Eb, Fb, kp, vpT);
    attn_kernel<<<1024, 256, 0, stream>>>(qb, kp, vpT, zsb);
    out_kernel<<<128, 256, 0, stream>>>(zsb, wob, (float*)d_out);
}